// Round 1
// baseline (866.818 us; speedup 1.0000x reference)
//
#include <hip/hip_runtime.h>
#include <cstddef>
#include <cstdint>

constexpr int DIMS = 128;
constexpr float BN_EPS = 1e-5f;

// ---------------- utility ----------------
__global__ void zero_k(int* __restrict__ ip, size_t ni, float* __restrict__ fp, size_t nf) {
  size_t i = (size_t)blockIdx.x * blockDim.x + threadIdx.x;
  if (i < ni) ip[i] = 0;
  if (i < nf) fp[i] = 0.f;
}

__global__ void deg_count_k(const int* __restrict__ dst, int* __restrict__ deg, int e) {
  int i = blockIdx.x * blockDim.x + threadIdx.x;
  if (i < e) atomicAdd(&deg[dst[i]], 1);
}

__global__ void dnorm_k(const int* __restrict__ deg, float* __restrict__ dn, int n) {
  int i = blockIdx.x * blockDim.x + threadIdx.x;
  if (i < n) dn[i] = rsqrtf(fmaxf((float)deg[i], 1.0f));
}

// ---------------- CSR build: 2-level exclusive scan of degrees ----------------
__global__ void scan1_k(const int* __restrict__ deg, int* __restrict__ bsum, int n) {
  __shared__ int lds[256];
  int t = threadIdx.x;
  int base = blockIdx.x * 1024;
  int s = 0;
  for (int i = t; i < 1024; i += 256) {
    int idx = base + i;
    s += (idx < n) ? deg[idx] : 0;
  }
  lds[t] = s; __syncthreads();
  for (int off = 128; off > 0; off >>= 1) {
    if (t < off) lds[t] += lds[t + off];
    __syncthreads();
  }
  if (t == 0) bsum[blockIdx.x] = lds[0];
}

__global__ void scan2_k(int* __restrict__ bsum, int nb, int* __restrict__ row_off, int n, int e) {
  __shared__ int lds[256];
  int t = threadIdx.x;
  int v = (t < nb) ? bsum[t] : 0;
  lds[t] = v; __syncthreads();
  for (int off = 1; off < 256; off <<= 1) {
    int add = (t >= off) ? lds[t - off] : 0;
    __syncthreads();
    lds[t] += add;
    __syncthreads();
  }
  if (t < nb) bsum[t] = lds[t] - v;  // exclusive base per chunk
  if (t == 0) row_off[n] = e;
}

__global__ void scan3_k(const int* __restrict__ deg, const int* __restrict__ bsum,
                        int* __restrict__ row_off, int n) {
  __shared__ int lds[256];
  int t = threadIdx.x;
  int base = blockIdx.x * 1024 + t * 4;
  int e0 = (base + 0 < n) ? deg[base + 0] : 0;
  int e1 = (base + 1 < n) ? deg[base + 1] : 0;
  int e2 = (base + 2 < n) ? deg[base + 2] : 0;
  int e3 = (base + 3 < n) ? deg[base + 3] : 0;
  int ts = e0 + e1 + e2 + e3;
  lds[t] = ts; __syncthreads();
  for (int off = 1; off < 256; off <<= 1) {
    int add = (t >= off) ? lds[t - off] : 0;
    __syncthreads();
    lds[t] += add;
    __syncthreads();
  }
  int ex = lds[t] - ts + bsum[blockIdx.x];
  if (base + 0 < n) row_off[base + 0] = ex;
  ex += e0;
  if (base + 1 < n) row_off[base + 1] = ex;
  ex += e1;
  if (base + 2 < n) row_off[base + 2] = ex;
  ex += e2;
  if (base + 3 < n) row_off[base + 3] = ex;
}

__global__ void build_adj_k(const int* __restrict__ src, const int* __restrict__ dst,
                            const int* __restrict__ row_off, int* __restrict__ cursor,
                            int* __restrict__ adj, int e) {
  int i = blockIdx.x * blockDim.x + threadIdx.x;
  if (i < e) {
    int dn = dst[i];
    int p = atomicAdd(&cursor[dn], 1);
    adj[row_off[dn] + p] = src[i];
  }
}

// ---------------- propagation hop (pull-based) + fused BN stats ----------------
// Y[n][d] = dnorm[n] * sum_{s in in(n)} dnorm[s] * (X[s][d]*a[d] + b[d])
template <bool AFF>
__global__ __launch_bounds__(128) void gather_k(
    const float* __restrict__ X, float* __restrict__ Y,
    const int* __restrict__ row_off, const int* __restrict__ adj,
    const float* __restrict__ dn, const float* __restrict__ a, const float* __restrict__ b,
    float* __restrict__ sumS, float* __restrict__ sqS, int n) {
  int d = threadIdx.x;
  int base = blockIdx.x * 64;
  float ad = AFF ? a[d] : 1.0f;
  float bd = AFF ? b[d] : 0.0f;
  float lsum = 0.f, lsq = 0.f;
  int rend = n - base; if (rend > 64) rend = 64;
  for (int r = 0; r < rend; ++r) {
    int node = base + r;
    int j0 = row_off[node], j1 = row_off[node + 1];
    float acc = 0.f;
    for (int j = j0; j < j1; ++j) {
      int s = adj[j];
      acc += dn[s] * fmaf(X[(size_t)s * DIMS + d], ad, bd);
    }
    float v = acc * dn[node];
    Y[(size_t)node * DIMS + d] = v;
    lsum += v;
    lsq += v * v;
  }
  atomicAdd(&sumS[d], lsum);
  atomicAdd(&sqS[d], lsq);
}

// ---------------- BN affine coefficients from accumulated stats ----------------
__global__ void affine_k(const float* __restrict__ sum, const float* __restrict__ sq,
                         const float* __restrict__ gamma, const float* __restrict__ beta,
                         float* __restrict__ a, float* __restrict__ b, float invn) {
  int d = threadIdx.x;
  float mu = sum[d] * invn;
  float var = sq[d] * invn - mu * mu;
  float rs = rsqrtf(var + BN_EPS);
  float ad = rs * gamma[d];
  a[d] = ad;
  b[d] = beta[d] - mu * ad;
}

// fold BN2-pre affine into conv weights: Wp[d][o]=a2[d]*W[d][o]; cp[o]=sum_d b2[d]*W[d][o]+cb[o]
__global__ void foldw_k(const float* __restrict__ W, const float* __restrict__ cb,
                        const float* __restrict__ a2, const float* __restrict__ b2,
                        float* __restrict__ Wp, float* __restrict__ cp) {
  int o = blockIdx.x;
  int d = threadIdx.x;
  float w = W[d * DIMS + o];
  Wp[d * DIMS + o] = a2[d] * w;
  __shared__ float red[128];
  red[d] = b2[d] * w;
  __syncthreads();
  for (int off = 64; off > 0; off >>= 1) {
    if (d < off) red[d] += red[d + off];
    __syncthreads();
  }
  if (d == 0) cp[o] = red[0] + cb[o];
}

// ---------------- Z = X @ Wp + cp  (+ fused BN2 stats) ----------------
__global__ __launch_bounds__(256) void matmul_k(
    const float* __restrict__ X, const float* __restrict__ W,
    const float* __restrict__ cp, float* __restrict__ Z,
    float* __restrict__ sumS, float* __restrict__ sqS, int n) {
  __shared__ float Xs[32 * DIMS];  // 16 KB
  int tid = threadIdx.x;
  int r0 = blockIdx.x * 32;
  {
    float4* dst4 = (float4*)Xs;
    const float4* src4 = (const float4*)(X + (size_t)r0 * DIMS);
    for (int i = tid; i < 32 * DIMS / 4; i += 256) {
      int row = r0 + i / (DIMS / 4);
      float4 v = make_float4(0.f, 0.f, 0.f, 0.f);
      if (row < n) v = src4[i];
      dst4[i] = v;
    }
  }
  __syncthreads();
  int tc = tid & 31, tr = tid >> 5;
  int c0 = tc * 4, rr0 = tr * 4;
  float acc[4][4] = {{0.f}};
#pragma unroll 4
  for (int k = 0; k < DIMS; ++k) {
    float4 w = *(const float4*)(W + k * DIMS + c0);
    float x0 = Xs[(rr0 + 0) * DIMS + k];
    float x1 = Xs[(rr0 + 1) * DIMS + k];
    float x2 = Xs[(rr0 + 2) * DIMS + k];
    float x3 = Xs[(rr0 + 3) * DIMS + k];
    acc[0][0] = fmaf(x0, w.x, acc[0][0]); acc[0][1] = fmaf(x0, w.y, acc[0][1]);
    acc[0][2] = fmaf(x0, w.z, acc[0][2]); acc[0][3] = fmaf(x0, w.w, acc[0][3]);
    acc[1][0] = fmaf(x1, w.x, acc[1][0]); acc[1][1] = fmaf(x1, w.y, acc[1][1]);
    acc[1][2] = fmaf(x1, w.z, acc[1][2]); acc[1][3] = fmaf(x1, w.w, acc[1][3]);
    acc[2][0] = fmaf(x2, w.x, acc[2][0]); acc[2][1] = fmaf(x2, w.y, acc[2][1]);
    acc[2][2] = fmaf(x2, w.z, acc[2][2]); acc[2][3] = fmaf(x2, w.w, acc[2][3]);
    acc[3][0] = fmaf(x3, w.x, acc[3][0]); acc[3][1] = fmaf(x3, w.y, acc[3][1]);
    acc[3][2] = fmaf(x3, w.z, acc[3][2]); acc[3][3] = fmaf(x3, w.w, acc[3][3]);
  }
  float4 cv = *(const float4*)(cp + c0);
  float ls[4] = {0.f, 0.f, 0.f, 0.f}, lq[4] = {0.f, 0.f, 0.f, 0.f};
#pragma unroll
  for (int i = 0; i < 4; ++i) {
    int row = r0 + rr0 + i;
    if (row < n) {
      float z0 = acc[i][0] + cv.x, z1 = acc[i][1] + cv.y;
      float z2 = acc[i][2] + cv.z, z3 = acc[i][3] + cv.w;
      *(float4*)(Z + (size_t)row * DIMS + c0) = make_float4(z0, z1, z2, z3);
      ls[0] += z0; ls[1] += z1; ls[2] += z2; ls[3] += z3;
      lq[0] += z0 * z0; lq[1] += z1 * z1; lq[2] += z2 * z2; lq[3] += z3 * z3;
    }
  }
  __syncthreads();  // done reading Xs, reuse as reduction scratch
  float* redS = Xs;
  float* redQ = Xs + 1024;
#pragma unroll
  for (int j = 0; j < 4; ++j) {
    redS[tr * DIMS + c0 + j] = ls[j];
    redQ[tr * DIMS + c0 + j] = lq[j];
  }
  __syncthreads();
  if (tid < DIMS) {
    float s = 0.f, q = 0.f;
#pragma unroll
    for (int t = 0; t < 8; ++t) { s += redS[t * DIMS + tid]; q += redQ[t * DIMS + tid]; }
    atomicAdd(&sumS[tid], s);
    atomicAdd(&sqS[tid], q);
  }
}

// ---------------- graph segment starts (node2graph is sorted) ----------------
__global__ void gstart_k(const int* __restrict__ n2g, int* __restrict__ gstart, int n, int G) {
  int i = blockIdx.x * blockDim.x + threadIdx.x;
  if (i >= n) return;
  int g = n2g[i];
  int gp = (i == 0) ? -1 : n2g[i - 1];
  for (int x = gp + 1; x <= g; ++x) gstart[x] = i;
  if (i == n - 1) {
    for (int x = g + 1; x <= G; ++x) gstart[x] = n;
  }
}

// ---------------- BN2-apply + relu + mean-pool + final 128->2 projection ----------------
__global__ __launch_bounds__(128) void pool_pred_k(
    const float* __restrict__ Z, const int* __restrict__ gstart,
    const float* __restrict__ a3, const float* __restrict__ b3,
    const float* __restrict__ pw, const float* __restrict__ pb,
    float* __restrict__ out) {
  int g = blockIdx.x;
  int d = threadIdx.x;
  int s = gstart[g], e = gstart[g + 1];
  float ad = a3[d], bd = b3[d];
  float acc = 0.f;
  for (int ni = s; ni < e; ++ni) {
    float v = fmaf(Z[(size_t)ni * DIMS + d], ad, bd);
    acc += fmaxf(v, 0.f);
  }
  float cnt = (float)(e - s);
  float mean = acc / fmaxf(cnt, 1.f);
  __shared__ float r0[128], r1[128];
  r0[d] = mean * pw[d * 2 + 0];
  r1[d] = mean * pw[d * 2 + 1];
  __syncthreads();
  for (int off = 64; off > 0; off >>= 1) {
    if (d < off) { r0[d] += r0[d + off]; r1[d] += r1[d + off]; }
    __syncthreads();
  }
  if (d == 0) {
    out[g * 2 + 0] = r0[0] + pb[0];
    out[g * 2 + 1] = r1[0] + pb[1];
  }
}

// ---------------- host launch ----------------
extern "C" void kernel_launch(void* const* d_in, const int* in_sizes, int n_in,
                              void* d_out, int out_size, void* d_ws, size_t ws_size,
                              hipStream_t stream) {
  const float* nfeat  = (const float*)d_in[0];
  const int*   src    = (const int*)d_in[1];
  const int*   dst    = (const int*)d_in[2];
  const int*   n2g    = (const int*)d_in[3];
  // d_in[4] = num_graphs (device scalar) — derived from out_size instead
  const float* conv_w = (const float*)d_in[5];
  const float* conv_b = (const float*)d_in[6];
  const float* gamma1 = (const float*)d_in[7];
  const float* beta1  = (const float*)d_in[8];
  const float* gamma2 = (const float*)d_in[9];
  const float* beta2  = (const float*)d_in[10];
  const float* pred_w = (const float*)d_in[11];
  const float* pred_b = (const float*)d_in[12];
  float* out = (float*)d_out;
  (void)n_in; (void)ws_size;

  const int n = in_sizes[0] / DIMS;
  const int e = in_sizes[1];
  const int g = out_size / 2;

  char* p = (char*)d_ws;
  auto alloc = [&](size_t bytes) { char* r = p; p += (bytes + 255) & ~(size_t)255; return r; };
  float* h1    = (float*)alloc((size_t)n * DIMS * 4);
  float* h2    = (float*)alloc((size_t)n * DIMS * 4);
  float* dnorm = (float*)alloc((size_t)n * 4);
  float* stat  = (float*)alloc(6 * DIMS * 4);
  float* affA  = (float*)alloc(3 * DIMS * 4);
  float* affB  = (float*)alloc(3 * DIMS * 4);
  float* Wp    = (float*)alloc(DIMS * DIMS * 4);
  float* cp    = (float*)alloc(DIMS * 4);
  int* deg_i   = (int*)alloc((size_t)n * 2 * 4);  // deg + cursor, contiguous for zeroing
  int* cursor  = deg_i + n;
  int* row_off = (int*)alloc(((size_t)n + 1) * 4);
  int* adj     = (int*)alloc((size_t)e * 4);
  int* bsum    = (int*)alloc(2048 * 4);
  int* gstart  = (int*)alloc(((size_t)g + 1) * 4);

  const int nb = (n + 1023) / 1024;  // <= 256 required (n <= 262144)
  const float invn = 1.0f / (float)n;
  const int gb = (n + 63) / 64;

  zero_k<<<dim3((2 * n + 255) / 256), dim3(256), 0, stream>>>(deg_i, (size_t)2 * n, stat, (size_t)6 * DIMS);
  deg_count_k<<<dim3((e + 255) / 256), dim3(256), 0, stream>>>(dst, deg_i, e);
  dnorm_k<<<dim3((n + 255) / 256), dim3(256), 0, stream>>>(deg_i, dnorm, n);
  scan1_k<<<dim3(nb), dim3(256), 0, stream>>>(deg_i, bsum, n);
  scan2_k<<<dim3(1), dim3(256), 0, stream>>>(bsum, nb, row_off, n, e);
  scan3_k<<<dim3(nb), dim3(256), 0, stream>>>(deg_i, bsum, row_off, n);
  build_adj_k<<<dim3((e + 255) / 256), dim3(256), 0, stream>>>(src, dst, row_off, cursor, adj, e);

  // hop 1: nfeat -> h1 (stats -> stage 0)
  gather_k<false><<<dim3(gb), dim3(128), 0, stream>>>(
      nfeat, h1, row_off, adj, dnorm, nullptr, nullptr, stat + 0, stat + DIMS, n);
  affine_k<<<dim3(1), dim3(DIMS), 0, stream>>>(stat + 0, stat + DIMS, gamma1, beta1,
                                               affA + 0, affB + 0, invn);
  // hop 2: BN1(h1) -> h2 (stats -> stage 1)
  gather_k<true><<<dim3(gb), dim3(128), 0, stream>>>(
      h1, h2, row_off, adj, dnorm, affA + 0, affB + 0, stat + 2 * DIMS, stat + 3 * DIMS, n);
  affine_k<<<dim3(1), dim3(DIMS), 0, stream>>>(stat + 2 * DIMS, stat + 3 * DIMS, gamma1, beta1,
                                               affA + DIMS, affB + DIMS, invn);
  // fold BN1(stage-2 affine) into conv weights, then Z = h2 @ Wp + cp (stats -> stage 2)
  foldw_k<<<dim3(DIMS), dim3(DIMS), 0, stream>>>(conv_w, conv_b, affA + DIMS, affB + DIMS, Wp, cp);
  matmul_k<<<dim3((n + 31) / 32), dim3(256), 0, stream>>>(h2, Wp, cp, h1,
                                                          stat + 4 * DIMS, stat + 5 * DIMS, n);
  affine_k<<<dim3(1), dim3(DIMS), 0, stream>>>(stat + 4 * DIMS, stat + 5 * DIMS, gamma2, beta2,
                                               affA + 2 * DIMS, affB + 2 * DIMS, invn);
  // pooling + prediction
  gstart_k<<<dim3((n + 255) / 256), dim3(256), 0, stream>>>(n2g, gstart, n, g);
  pool_pred_k<<<dim3(g), dim3(DIMS), 0, stream>>>(h1, gstart, affA + 2 * DIMS, affB + 2 * DIMS,
                                                  pred_w, pred_b, out);
}

// Round 2
// 859.691 us; speedup vs baseline: 1.0083x; 1.0083x over previous
//
#include <hip/hip_runtime.h>
#include <hip/hip_fp16.h>
#include <cstddef>
#include <cstdint>

constexpr int DIMS = 128;
constexpr float BN_EPS = 1e-5f;

// ---------------- utility ----------------
__global__ void zero_k(int* __restrict__ ip, size_t ni, float* __restrict__ fp, size_t nf) {
  size_t i = (size_t)blockIdx.x * blockDim.x + threadIdx.x;
  if (i < ni) ip[i] = 0;
  if (i < nf) fp[i] = 0.f;
}

// fp32 -> fp16 conversion (grid-stride, float4 granularity)
__global__ void cvt_k(const float* __restrict__ in, __half2* __restrict__ out, size_t n4) {
  size_t i = (size_t)blockIdx.x * blockDim.x + threadIdx.x;
  size_t stride = (size_t)gridDim.x * blockDim.x;
  const float4* in4 = (const float4*)in;
  for (; i < n4; i += stride) {
    float4 v = in4[i];
    out[2 * i + 0] = __floats2half2_rn(v.x, v.y);
    out[2 * i + 1] = __floats2half2_rn(v.z, v.w);
  }
}

__global__ void deg_count_k(const int* __restrict__ dst, int* __restrict__ deg, int e) {
  int i = blockIdx.x * blockDim.x + threadIdx.x;
  if (i < e) atomicAdd(&deg[dst[i]], 1);
}

__global__ void dnorm_k(const int* __restrict__ deg, float* __restrict__ dn, int n) {
  int i = blockIdx.x * blockDim.x + threadIdx.x;
  if (i < n) dn[i] = rsqrtf(fmaxf((float)deg[i], 1.0f));
}

// ---------------- CSR build: 2-level exclusive scan of degrees ----------------
__global__ void scan1_k(const int* __restrict__ deg, int* __restrict__ bsum, int n) {
  __shared__ int lds[256];
  int t = threadIdx.x;
  int base = blockIdx.x * 1024;
  int s = 0;
  for (int i = t; i < 1024; i += 256) {
    int idx = base + i;
    s += (idx < n) ? deg[idx] : 0;
  }
  lds[t] = s; __syncthreads();
  for (int off = 128; off > 0; off >>= 1) {
    if (t < off) lds[t] += lds[t + off];
    __syncthreads();
  }
  if (t == 0) bsum[blockIdx.x] = lds[0];
}

__global__ void scan2_k(int* __restrict__ bsum, int nb, int* __restrict__ row_off, int n, int e) {
  __shared__ int lds[256];
  int t = threadIdx.x;
  int v = (t < nb) ? bsum[t] : 0;
  lds[t] = v; __syncthreads();
  for (int off = 1; off < 256; off <<= 1) {
    int add = (t >= off) ? lds[t - off] : 0;
    __syncthreads();
    lds[t] += add;
    __syncthreads();
  }
  if (t < nb) bsum[t] = lds[t] - v;  // exclusive base per chunk
  if (t == 0) row_off[n] = e;
}

__global__ void scan3_k(const int* __restrict__ deg, const int* __restrict__ bsum,
                        int* __restrict__ row_off, int n) {
  __shared__ int lds[256];
  int t = threadIdx.x;
  int base = blockIdx.x * 1024 + t * 4;
  int e0 = (base + 0 < n) ? deg[base + 0] : 0;
  int e1 = (base + 1 < n) ? deg[base + 1] : 0;
  int e2 = (base + 2 < n) ? deg[base + 2] : 0;
  int e3 = (base + 3 < n) ? deg[base + 3] : 0;
  int ts = e0 + e1 + e2 + e3;
  lds[t] = ts; __syncthreads();
  for (int off = 1; off < 256; off <<= 1) {
    int add = (t >= off) ? lds[t - off] : 0;
    __syncthreads();
    lds[t] += add;
    __syncthreads();
  }
  int ex = lds[t] - ts + bsum[blockIdx.x];
  if (base + 0 < n) row_off[base + 0] = ex;
  ex += e0;
  if (base + 1 < n) row_off[base + 1] = ex;
  ex += e1;
  if (base + 2 < n) row_off[base + 2] = ex;
  ex += e2;
  if (base + 3 < n) row_off[base + 3] = ex;
}

__global__ void build_adj_k(const int* __restrict__ src, const int* __restrict__ dst,
                            const int* __restrict__ row_off, int* __restrict__ cursor,
                            int* __restrict__ adj, int e) {
  int i = blockIdx.x * blockDim.x + threadIdx.x;
  if (i < e) {
    int dn = dst[i];
    int p = atomicAdd(&cursor[dn], 1);
    adj[row_off[dn] + p] = src[i];
  }
}

// ---------------- propagation hop (pull-based, fp16 rows) + fused BN stats ----------------
// AFF=false:  Y[n][f] = dn[n] * sum_s dn[s]*X[s][f];  also wsum[n] = sum_s dn[s]
// AFF=true:   Y[n][f] = dn[n] * (a[f]*sum_s dn[s]*X[s][f] + b[f]*wsum[n])
//   (algebraically identical to gathering a[f]*X+b[f] per edge)
// Block: 256 threads = 4 waves; wave w handles 8 consecutive nodes; lane l owns features 2l,2l+1.
template <bool AFF>
__global__ __launch_bounds__(256) void gather_k(
    const __half2* __restrict__ X, __half2* __restrict__ Y,
    const int* __restrict__ row_off, const int* __restrict__ adj,
    const float* __restrict__ dn, float* __restrict__ wsum,
    const float* __restrict__ a, const float* __restrict__ b,
    float* __restrict__ sumS, float* __restrict__ sqS, int n) {
  int tid = threadIdx.x;
  int l = tid & 63, w = tid >> 6;
  int f0 = 2 * l;
  float af0 = 0.f, bf0 = 0.f, af1 = 0.f, bf1 = 0.f;
  if (AFF) { af0 = a[f0]; bf0 = b[f0]; af1 = a[f0 + 1]; bf1 = b[f0 + 1]; }
  float s0 = 0.f, s1 = 0.f, q0 = 0.f, q1 = 0.f;
  int base = blockIdx.x * 32 + w * 8;
  for (int r = 0; r < 8; ++r) {
    int node = base + r;
    if (node >= n) break;
    int j0 = row_off[node], j1 = row_off[node + 1];
    float acc0 = 0.f, acc1 = 0.f, ds = 0.f;
    int j = j0;
    for (; j + 2 <= j1; j += 2) {
      int sA = adj[j], sB = adj[j + 1];
      float dA = dn[sA], dB = dn[sB];
      float2 xA = __half22float2(X[(size_t)sA * 64 + l]);
      float2 xB = __half22float2(X[(size_t)sB * 64 + l]);
      acc0 += dA * xA.x + dB * xB.x;
      acc1 += dA * xA.y + dB * xB.y;
      if constexpr (!AFF) ds += dA + dB;
    }
    if (j < j1) {
      int sA = adj[j];
      float dA = dn[sA];
      float2 xA = __half22float2(X[(size_t)sA * 64 + l]);
      acc0 += dA * xA.x;
      acc1 += dA * xA.y;
      if constexpr (!AFF) ds += dA;
    }
    float dnn = dn[node];
    float v0, v1;
    if constexpr (AFF) {
      float wsn = wsum[node];
      v0 = (af0 * acc0 + bf0 * wsn) * dnn;
      v1 = (af1 * acc1 + bf1 * wsn) * dnn;
    } else {
      v0 = acc0 * dnn;
      v1 = acc1 * dnn;
      if (l == 0) wsum[node] = ds;
    }
    Y[(size_t)node * 64 + l] = __floats2half2_rn(v0, v1);
    s0 += v0; s1 += v1; q0 += v0 * v0; q1 += v1 * v1;
  }
  // block-level stats reduction, then 1 atomic per (feature,stat) per block
  __shared__ float red[4][256];
  red[w][l] = s0; red[w][64 + l] = s1; red[w][128 + l] = q0; red[w][192 + l] = q1;
  __syncthreads();
  float t = red[0][tid] + red[1][tid] + red[2][tid] + red[3][tid];
  int comp = tid >> 6, li = tid & 63;
  float* dstp = (comp & 2) ? sqS : sumS;
  atomicAdd(&dstp[2 * li + (comp & 1)], t);
}

// ---------------- BN affine coefficients from accumulated stats ----------------
__global__ void affine_k(const float* __restrict__ sum, const float* __restrict__ sq,
                         const float* __restrict__ gamma, const float* __restrict__ beta,
                         float* __restrict__ a, float* __restrict__ b, float invn) {
  int d = threadIdx.x;
  float mu = sum[d] * invn;
  float var = sq[d] * invn - mu * mu;
  float rs = rsqrtf(var + BN_EPS);
  float ad = rs * gamma[d];
  a[d] = ad;
  b[d] = beta[d] - mu * ad;
}

// fold pre-matmul affine into conv weights: Wp[d][o]=a2[d]*W[d][o]; cp[o]=sum_d b2[d]*W[d][o]+cb[o]
__global__ void foldw_k(const float* __restrict__ W, const float* __restrict__ cb,
                        const float* __restrict__ a2, const float* __restrict__ b2,
                        float* __restrict__ Wp, float* __restrict__ cp) {
  int o = blockIdx.x;
  int d = threadIdx.x;
  float w = W[d * DIMS + o];
  Wp[d * DIMS + o] = a2[d] * w;
  __shared__ float red[128];
  red[d] = b2[d] * w;
  __syncthreads();
  for (int off = 64; off > 0; off >>= 1) {
    if (d < off) red[d] += red[d + off];
    __syncthreads();
  }
  if (d == 0) cp[o] = red[0] + cb[o];
}

// ---------------- Z = X @ Wp + cp  (fp16 in, fp16 out, fused BN stats) ----------------
__global__ __launch_bounds__(256) void matmul_k(
    const __half2* __restrict__ X, const float* __restrict__ W,
    const float* __restrict__ cp, __half2* __restrict__ Z,
    float* __restrict__ sumS, float* __restrict__ sqS, int n) {
  __shared__ float Xs[32 * DIMS];  // 16 KB
  int tid = threadIdx.x;
  int r0 = blockIdx.x * 32;
  {
    float2* dst2 = (float2*)Xs;
    for (int i = tid; i < 32 * 64; i += 256) {
      int row = r0 + (i >> 6);
      float2 v = make_float2(0.f, 0.f);
      if (row < n) v = __half22float2(X[(size_t)row * 64 + (i & 63)]);
      dst2[i] = v;
    }
  }
  __syncthreads();
  int tc = tid & 31, tr = tid >> 5;
  int c0 = tc * 4, rr0 = tr * 4;
  float acc[4][4] = {{0.f}};
#pragma unroll 4
  for (int k = 0; k < DIMS; ++k) {
    float4 w = *(const float4*)(W + k * DIMS + c0);
    float x0 = Xs[(rr0 + 0) * DIMS + k];
    float x1 = Xs[(rr0 + 1) * DIMS + k];
    float x2 = Xs[(rr0 + 2) * DIMS + k];
    float x3 = Xs[(rr0 + 3) * DIMS + k];
    acc[0][0] = fmaf(x0, w.x, acc[0][0]); acc[0][1] = fmaf(x0, w.y, acc[0][1]);
    acc[0][2] = fmaf(x0, w.z, acc[0][2]); acc[0][3] = fmaf(x0, w.w, acc[0][3]);
    acc[1][0] = fmaf(x1, w.x, acc[1][0]); acc[1][1] = fmaf(x1, w.y, acc[1][1]);
    acc[1][2] = fmaf(x1, w.z, acc[1][2]); acc[1][3] = fmaf(x1, w.w, acc[1][3]);
    acc[2][0] = fmaf(x2, w.x, acc[2][0]); acc[2][1] = fmaf(x2, w.y, acc[2][1]);
    acc[2][2] = fmaf(x2, w.z, acc[2][2]); acc[2][3] = fmaf(x2, w.w, acc[2][3]);
    acc[3][0] = fmaf(x3, w.x, acc[3][0]); acc[3][1] = fmaf(x3, w.y, acc[3][1]);
    acc[3][2] = fmaf(x3, w.z, acc[3][2]); acc[3][3] = fmaf(x3, w.w, acc[3][3]);
  }
  float4 cv = *(const float4*)(cp + c0);
  float ls[4] = {0.f, 0.f, 0.f, 0.f}, lq[4] = {0.f, 0.f, 0.f, 0.f};
#pragma unroll
  for (int i = 0; i < 4; ++i) {
    int row = r0 + rr0 + i;
    if (row < n) {
      float z0 = acc[i][0] + cv.x, z1 = acc[i][1] + cv.y;
      float z2 = acc[i][2] + cv.z, z3 = acc[i][3] + cv.w;
      Z[(size_t)row * 64 + (c0 >> 1) + 0] = __floats2half2_rn(z0, z1);
      Z[(size_t)row * 64 + (c0 >> 1) + 1] = __floats2half2_rn(z2, z3);
      ls[0] += z0; ls[1] += z1; ls[2] += z2; ls[3] += z3;
      lq[0] += z0 * z0; lq[1] += z1 * z1; lq[2] += z2 * z2; lq[3] += z3 * z3;
    }
  }
  __syncthreads();  // done reading Xs, reuse as reduction scratch
  float* redS = Xs;
  float* redQ = Xs + 1024;
#pragma unroll
  for (int j = 0; j < 4; ++j) {
    redS[tr * DIMS + c0 + j] = ls[j];
    redQ[tr * DIMS + c0 + j] = lq[j];
  }
  __syncthreads();
  if (tid < DIMS) {
    float s = 0.f, q = 0.f;
#pragma unroll
    for (int t = 0; t < 8; ++t) { s += redS[t * DIMS + tid]; q += redQ[t * DIMS + tid]; }
    atomicAdd(&sumS[tid], s);
    atomicAdd(&sqS[tid], q);
  }
}

// ---------------- graph segment starts (node2graph is sorted) ----------------
__global__ void gstart_k(const int* __restrict__ n2g, int* __restrict__ gstart, int n, int G) {
  int i = blockIdx.x * blockDim.x + threadIdx.x;
  if (i >= n) return;
  int g = n2g[i];
  int gp = (i == 0) ? -1 : n2g[i - 1];
  for (int x = gp + 1; x <= g; ++x) gstart[x] = i;
  if (i == n - 1) {
    for (int x = g + 1; x <= G; ++x) gstart[x] = n;
  }
}

// ---------------- BN2-apply + relu + mean-pool + final 128->2 projection ----------------
__global__ __launch_bounds__(256) void pool_pred_k(
    const __half2* __restrict__ Z, const int* __restrict__ gstart,
    const float* __restrict__ a3, const float* __restrict__ b3,
    const float* __restrict__ pw, const float* __restrict__ pb,
    float* __restrict__ out) {
  int g = blockIdx.x;
  int tid = threadIdx.x;
  int l = tid & 63, w = tid >> 6;
  int f0 = 2 * l;
  float a0 = a3[f0], b0 = b3[f0], a1 = a3[f0 + 1], b1 = b3[f0 + 1];
  int s = gstart[g], e = gstart[g + 1];
  float acc0 = 0.f, acc1 = 0.f;
  for (int ni = s + w; ni < e; ni += 4) {
    float2 z = __half22float2(Z[(size_t)ni * 64 + l]);
    acc0 += fmaxf(fmaf(z.x, a0, b0), 0.f);
    acc1 += fmaxf(fmaf(z.y, a1, b1), 0.f);
  }
  float inv = 1.f / fmaxf((float)(e - s), 1.f);
  float c0 = acc0 * inv * pw[f0 * 2 + 0] + acc1 * inv * pw[(f0 + 1) * 2 + 0];
  float c1 = acc0 * inv * pw[f0 * 2 + 1] + acc1 * inv * pw[(f0 + 1) * 2 + 1];
  __shared__ float r[2][256];
  r[0][tid] = c0; r[1][tid] = c1;
  __syncthreads();
  for (int off = 128; off > 0; off >>= 1) {
    if (tid < off) { r[0][tid] += r[0][tid + off]; r[1][tid] += r[1][tid + off]; }
    __syncthreads();
  }
  if (tid == 0) {
    out[g * 2 + 0] = r[0][0] + pb[0];
    out[g * 2 + 1] = r[1][0] + pb[1];
  }
}

// ---------------- host launch ----------------
extern "C" void kernel_launch(void* const* d_in, const int* in_sizes, int n_in,
                              void* d_out, int out_size, void* d_ws, size_t ws_size,
                              hipStream_t stream) {
  const float* nfeat  = (const float*)d_in[0];
  const int*   src    = (const int*)d_in[1];
  const int*   dst    = (const int*)d_in[2];
  const int*   n2g    = (const int*)d_in[3];
  // d_in[4] = num_graphs (device scalar) — derived from out_size instead
  const float* conv_w = (const float*)d_in[5];
  const float* conv_b = (const float*)d_in[6];
  const float* gamma1 = (const float*)d_in[7];
  const float* beta1  = (const float*)d_in[8];
  const float* gamma2 = (const float*)d_in[9];
  const float* beta2  = (const float*)d_in[10];
  const float* pred_w = (const float*)d_in[11];
  const float* pred_b = (const float*)d_in[12];
  float* out = (float*)d_out;
  (void)n_in; (void)ws_size;

  const int n = in_sizes[0] / DIMS;
  const int e = in_sizes[1];
  const int g = out_size / 2;

  char* p = (char*)d_ws;
  auto alloc = [&](size_t bytes) { char* r = p; p += (bytes + 255) & ~(size_t)255; return r; };
  __half2* Xh  = (__half2*)alloc((size_t)n * DIMS * 2);
  __half2* Y1h = (__half2*)alloc((size_t)n * DIMS * 2);
  __half2* Y2h = (__half2*)alloc((size_t)n * DIMS * 2);
  __half2* Zh  = (__half2*)alloc((size_t)n * DIMS * 2);
  float* dnorm = (float*)alloc((size_t)n * 4);
  float* wsum  = (float*)alloc((size_t)n * 4);
  float* stat  = (float*)alloc(6 * DIMS * 4);
  float* affA  = (float*)alloc(3 * DIMS * 4);
  float* affB  = (float*)alloc(3 * DIMS * 4);
  float* Wp    = (float*)alloc(DIMS * DIMS * 4);
  float* cp    = (float*)alloc(DIMS * 4);
  int* deg_i   = (int*)alloc((size_t)n * 2 * 4);  // deg + cursor, contiguous for zeroing
  int* cursor  = deg_i + n;
  int* row_off = (int*)alloc(((size_t)n + 1) * 4);
  int* adj     = (int*)alloc((size_t)e * 4);
  int* bsum    = (int*)alloc(2048 * 4);
  int* gstart  = (int*)alloc(((size_t)g + 1) * 4);

  const int nb = (n + 1023) / 1024;  // <= 256 required (n <= 262144)
  const float invn = 1.0f / (float)n;
  const int gb = (n + 31) / 32;

  zero_k<<<dim3((2 * n + 255) / 256), dim3(256), 0, stream>>>(deg_i, (size_t)2 * n, stat, (size_t)6 * DIMS);
  cvt_k<<<dim3(2048), dim3(256), 0, stream>>>(nfeat, Xh, (size_t)n * 32);
  deg_count_k<<<dim3((e + 255) / 256), dim3(256), 0, stream>>>(dst, deg_i, e);
  dnorm_k<<<dim3((n + 255) / 256), dim3(256), 0, stream>>>(deg_i, dnorm, n);
  scan1_k<<<dim3(nb), dim3(256), 0, stream>>>(deg_i, bsum, n);
  scan2_k<<<dim3(1), dim3(256), 0, stream>>>(bsum, nb, row_off, n, e);
  scan3_k<<<dim3(nb), dim3(256), 0, stream>>>(deg_i, bsum, row_off, n);
  build_adj_k<<<dim3((e + 255) / 256), dim3(256), 0, stream>>>(src, dst, row_off, cursor, adj, e);

  // hop 1: Xh -> Y1h (stats -> stage 0, wsum computed)
  gather_k<false><<<dim3(gb), dim3(256), 0, stream>>>(
      Xh, Y1h, row_off, adj, dnorm, wsum, nullptr, nullptr, stat + 0, stat + DIMS, n);
  affine_k<<<dim3(1), dim3(DIMS), 0, stream>>>(stat + 0, stat + DIMS, gamma1, beta1,
                                               affA + 0, affB + 0, invn);
  // hop 2: BN1(Y1h) -> Y2h (stats -> stage 1)
  gather_k<true><<<dim3(gb), dim3(256), 0, stream>>>(
      Y1h, Y2h, row_off, adj, dnorm, wsum, affA + 0, affB + 0, stat + 2 * DIMS, stat + 3 * DIMS, n);
  affine_k<<<dim3(1), dim3(DIMS), 0, stream>>>(stat + 2 * DIMS, stat + 3 * DIMS, gamma1, beta1,
                                               affA + DIMS, affB + DIMS, invn);
  // fold stage-1 affine into conv weights, then Z = Y2h @ Wp + cp (stats -> stage 2)
  foldw_k<<<dim3(DIMS), dim3(DIMS), 0, stream>>>(conv_w, conv_b, affA + DIMS, affB + DIMS, Wp, cp);
  matmul_k<<<dim3((n + 31) / 32), dim3(256), 0, stream>>>(Y2h, Wp, cp, Zh,
                                                          stat + 4 * DIMS, stat + 5 * DIMS, n);
  affine_k<<<dim3(1), dim3(DIMS), 0, stream>>>(stat + 4 * DIMS, stat + 5 * DIMS, gamma2, beta2,
                                               affA + 2 * DIMS, affB + 2 * DIMS, invn);
  // pooling + prediction
  gstart_k<<<dim3((n + 255) / 256), dim3(256), 0, stream>>>(n2g, gstart, n, g);
  pool_pred_k<<<dim3(g), dim3(256), 0, stream>>>(Zh, gstart, affA + 2 * DIMS, affB + 2 * DIMS,
                                                 pred_w, pred_b, out);
}

// Round 3
// 457.349 us; speedup vs baseline: 1.8953x; 1.8797x over previous
//
#include <hip/hip_runtime.h>
#include <hip/hip_fp16.h>
#include <cstddef>
#include <cstdint>

constexpr int DIMS = 128;
constexpr float BN_EPS = 1e-5f;
constexpr int NSH = 64;  // stat shadow copies (kills same-address atomic serialization)

// ---------------- utility ----------------
__global__ void zero_k(int* __restrict__ ip, size_t ni, float* __restrict__ fp, size_t nf) {
  size_t i = (size_t)blockIdx.x * blockDim.x + threadIdx.x;
  if (i < ni) ip[i] = 0;
  if (i < nf) fp[i] = 0.f;
}

// fp32 -> fp16 conversion with dn pre-scale: Xp[s] = dn[s] * nfeat[s]
__global__ void cvt_k(const float* __restrict__ in, uint32_t* __restrict__ out,
                      const float* __restrict__ dn, size_t n64) {
  size_t i = (size_t)blockIdx.x * blockDim.x + threadIdx.x;
  size_t stride = (size_t)gridDim.x * blockDim.x;
  const float2* in2 = (const float2*)in;
  for (; i < n64; i += stride) {
    float d = dn[i >> 6];
    float2 v = in2[i];
    __half2 h = __floats2half2_rn(v.x * d, v.y * d);
    out[i] = *(const uint32_t*)&h;
  }
}

__global__ void deg_count_k(const int* __restrict__ dst, int* __restrict__ deg, int e) {
  int i = blockIdx.x * blockDim.x + threadIdx.x;
  if (i < e) atomicAdd(&deg[dst[i]], 1);
}

__global__ void dnorm_k(const int* __restrict__ deg, float* __restrict__ dn, int n) {
  int i = blockIdx.x * blockDim.x + threadIdx.x;
  if (i < n) dn[i] = rsqrtf(fmaxf((float)deg[i], 1.0f));
}

// ---------------- CSR build: 2-level exclusive scan of degrees ----------------
__global__ void scan1_k(const int* __restrict__ deg, int* __restrict__ bsum, int n) {
  __shared__ int lds[256];
  int t = threadIdx.x;
  int base = blockIdx.x * 1024;
  int s = 0;
  for (int i = t; i < 1024; i += 256) {
    int idx = base + i;
    s += (idx < n) ? deg[idx] : 0;
  }
  lds[t] = s; __syncthreads();
  for (int off = 128; off > 0; off >>= 1) {
    if (t < off) lds[t] += lds[t + off];
    __syncthreads();
  }
  if (t == 0) bsum[blockIdx.x] = lds[0];
}

__global__ void scan2_k(int* __restrict__ bsum, int nb, int* __restrict__ row_off, int n, int e) {
  __shared__ int lds[256];
  int t = threadIdx.x;
  int v = (t < nb) ? bsum[t] : 0;
  lds[t] = v; __syncthreads();
  for (int off = 1; off < 256; off <<= 1) {
    int add = (t >= off) ? lds[t - off] : 0;
    __syncthreads();
    lds[t] += add;
    __syncthreads();
  }
  if (t < nb) bsum[t] = lds[t] - v;  // exclusive base per chunk
  if (t == 0) row_off[n] = e;
}

__global__ void scan3_k(const int* __restrict__ deg, const int* __restrict__ bsum,
                        int* __restrict__ row_off, int n) {
  __shared__ int lds[256];
  int t = threadIdx.x;
  int base = blockIdx.x * 1024 + t * 4;
  int e0 = (base + 0 < n) ? deg[base + 0] : 0;
  int e1 = (base + 1 < n) ? deg[base + 1] : 0;
  int e2 = (base + 2 < n) ? deg[base + 2] : 0;
  int e3 = (base + 3 < n) ? deg[base + 3] : 0;
  int ts = e0 + e1 + e2 + e3;
  lds[t] = ts; __syncthreads();
  for (int off = 1; off < 256; off <<= 1) {
    int add = (t >= off) ? lds[t - off] : 0;
    __syncthreads();
    lds[t] += add;
    __syncthreads();
  }
  int ex = lds[t] - ts + bsum[blockIdx.x];
  if (base + 0 < n) row_off[base + 0] = ex;
  ex += e0;
  if (base + 1 < n) row_off[base + 1] = ex;
  ex += e1;
  if (base + 2 < n) row_off[base + 2] = ex;
  ex += e2;
  if (base + 3 < n) row_off[base + 3] = ex;
}

__global__ void build_adj_k(const int* __restrict__ src, const int* __restrict__ dst,
                            const int* __restrict__ row_off, int* __restrict__ cursor,
                            int* __restrict__ adj, int e) {
  int i = blockIdx.x * blockDim.x + threadIdx.x;
  if (i < e) {
    int dn = dst[i];
    int p = atomicAdd(&cursor[dn], 1);
    adj[row_off[dn] + p] = src[i];
  }
}

// ---------------- propagation hop: one WAVE per node, 8-deep MLP ----------------
// Inputs are pre-scaled rows (Xp = dn[s]*x[s], or W1 = dn[s]*h1[s]).
// AFF=false (hop1): acc = sum Xp[s];  h1 = dn[n]*acc;  stats(h1);  store W1 = dn[n]*h1.
//                   also wsum[n] = sum dn[s].
// AFF=true  (hop2): acc = sum W1[s];  h2 = dn[n]*(a*acc + b*wsum[n]);  stats(h2); store h2.
template <bool AFF>
__global__ __launch_bounds__(256) void gather_k(
    const uint32_t* __restrict__ Xu, uint32_t* __restrict__ Yout,
    const int* __restrict__ row_off, const int* __restrict__ adj,
    const float* __restrict__ dn, float* __restrict__ wsum,
    const float* __restrict__ a, const float* __restrict__ b,
    float* __restrict__ sumS, float* __restrict__ sqS, int n) {
  int tid = threadIdx.x;
  int l = tid & 63, w = tid >> 6;
  int node = __builtin_amdgcn_readfirstlane(blockIdx.x * 4 + w);  // wave-uniform
  int f0 = 2 * l;
  float s0 = 0.f, s1 = 0.f, q0 = 0.f, q1 = 0.f;
  if (node < n) {
    int j0 = row_off[node], j1 = row_off[node + 1];
    float acc0 = 0.f, acc1 = 0.f, ds = 0.f;
    for (int j = j0; j < j1; j += 8) {
      uint32_t xv[8];
      float dv[8];
#pragma unroll
      for (int t = 0; t < 8; ++t) {
        int jj = j + t;
        if (jj < j1) {  // uniform branch: whole wave takes it together
          int sj = adj[jj];
          xv[t] = Xu[(size_t)sj * 64 + l];
          if constexpr (!AFF) dv[t] = dn[sj];
        } else {
          xv[t] = 0u;
          if constexpr (!AFF) dv[t] = 0.f;
        }
      }
#pragma unroll
      for (int t = 0; t < 8; ++t) {
        float2 x = __half22float2(*(const __half2*)&xv[t]);
        acc0 += x.x;
        acc1 += x.y;
        if constexpr (!AFF) ds += dv[t];
      }
    }
    float dnn = dn[node];
    float v0, v1;
    if constexpr (AFF) {
      float wsn = wsum[node];
      v0 = dnn * fmaf(a[f0], acc0, b[f0] * wsn);
      v1 = dnn * fmaf(a[f0 + 1], acc1, b[f0 + 1] * wsn);
      __half2 hv = __floats2half2_rn(v0, v1);  // store h2
      Yout[(size_t)node * 64 + l] = *(const uint32_t*)&hv;
    } else {
      v0 = acc0 * dnn;  // h1
      v1 = acc1 * dnn;
      __half2 hv = __floats2half2_rn(v0 * dnn, v1 * dnn);  // store W1 = dn^2*acc
      Yout[(size_t)node * 64 + l] = *(const uint32_t*)&hv;
      if (l == 0) wsum[node] = ds;
    }
    s0 = v0; s1 = v1; q0 = v0 * v0; q1 = v1 * v1;
  }
  // block-level stats reduction, then 1 atomic per (feature,stat) per block (shadowed)
  __shared__ float red[4][256];
  red[w][l] = s0; red[w][64 + l] = s1; red[w][128 + l] = q0; red[w][192 + l] = q1;
  __syncthreads();
  float t = red[0][tid] + red[1][tid] + red[2][tid] + red[3][tid];
  int comp = tid >> 6, li = tid & 63;
  int sh = blockIdx.x & (NSH - 1);
  float* dstp = ((comp & 2) ? sqS : sumS) + sh * DIMS;
  atomicAdd(&dstp[2 * li + (comp & 1)], t);
}

// ---------------- BN affine coefficients (reduces NSH shadow copies) ----------------
__global__ void affine_k(const float* __restrict__ sum, const float* __restrict__ sq,
                         const float* __restrict__ gamma, const float* __restrict__ beta,
                         float* __restrict__ a, float* __restrict__ b, float invn) {
  int d = threadIdx.x;
  float s = 0.f, q = 0.f;
  for (int k = 0; k < NSH; ++k) { s += sum[k * DIMS + d]; q += sq[k * DIMS + d]; }
  float mu = s * invn;
  float var = q * invn - mu * mu;
  float rs = rsqrtf(var + BN_EPS);
  float ad = rs * gamma[d];
  a[d] = ad;
  b[d] = beta[d] - mu * ad;
}

// fold pre-matmul affine into conv weights: Wp[d][o]=a2[d]*W[d][o]; cp[o]=sum_d b2[d]*W[d][o]+cb[o]
__global__ void foldw_k(const float* __restrict__ W, const float* __restrict__ cb,
                        const float* __restrict__ a2, const float* __restrict__ b2,
                        float* __restrict__ Wp, float* __restrict__ cp) {
  int o = blockIdx.x;
  int d = threadIdx.x;
  float w = W[d * DIMS + o];
  Wp[d * DIMS + o] = a2[d] * w;
  __shared__ float red[128];
  red[d] = b2[d] * w;
  __syncthreads();
  for (int off = 64; off > 0; off >>= 1) {
    if (d < off) red[d] += red[d + off];
    __syncthreads();
  }
  if (d == 0) cp[o] = red[0] + cb[o];
}

// ---------------- Z = X @ Wp + cp  (fp16 in, fp16 out, fused BN stats) ----------------
__global__ __launch_bounds__(256) void matmul_k(
    const __half2* __restrict__ X, const float* __restrict__ W,
    const float* __restrict__ cp, __half2* __restrict__ Z,
    float* __restrict__ sumS, float* __restrict__ sqS, int n) {
  __shared__ float Xs[32 * DIMS];  // 16 KB
  int tid = threadIdx.x;
  int r0 = blockIdx.x * 32;
  {
    float2* dst2 = (float2*)Xs;
    for (int i = tid; i < 32 * 64; i += 256) {
      int row = r0 + (i >> 6);
      float2 v = make_float2(0.f, 0.f);
      if (row < n) v = __half22float2(X[(size_t)row * 64 + (i & 63)]);
      dst2[i] = v;
    }
  }
  __syncthreads();
  int tc = tid & 31, tr = tid >> 5;
  int c0 = tc * 4, rr0 = tr * 4;
  float acc[4][4] = {{0.f}};
#pragma unroll 4
  for (int k = 0; k < DIMS; ++k) {
    float4 w = *(const float4*)(W + k * DIMS + c0);
    float x0 = Xs[(rr0 + 0) * DIMS + k];
    float x1 = Xs[(rr0 + 1) * DIMS + k];
    float x2 = Xs[(rr0 + 2) * DIMS + k];
    float x3 = Xs[(rr0 + 3) * DIMS + k];
    acc[0][0] = fmaf(x0, w.x, acc[0][0]); acc[0][1] = fmaf(x0, w.y, acc[0][1]);
    acc[0][2] = fmaf(x0, w.z, acc[0][2]); acc[0][3] = fmaf(x0, w.w, acc[0][3]);
    acc[1][0] = fmaf(x1, w.x, acc[1][0]); acc[1][1] = fmaf(x1, w.y, acc[1][1]);
    acc[1][2] = fmaf(x1, w.z, acc[1][2]); acc[1][3] = fmaf(x1, w.w, acc[1][3]);
    acc[2][0] = fmaf(x2, w.x, acc[2][0]); acc[2][1] = fmaf(x2, w.y, acc[2][1]);
    acc[2][2] = fmaf(x2, w.z, acc[2][2]); acc[2][3] = fmaf(x2, w.w, acc[2][3]);
    acc[3][0] = fmaf(x3, w.x, acc[3][0]); acc[3][1] = fmaf(x3, w.y, acc[3][1]);
    acc[3][2] = fmaf(x3, w.z, acc[3][2]); acc[3][3] = fmaf(x3, w.w, acc[3][3]);
  }
  float4 cv = *(const float4*)(cp + c0);
  float ls[4] = {0.f, 0.f, 0.f, 0.f}, lq[4] = {0.f, 0.f, 0.f, 0.f};
#pragma unroll
  for (int i = 0; i < 4; ++i) {
    int row = r0 + rr0 + i;
    if (row < n) {
      float z0 = acc[i][0] + cv.x, z1 = acc[i][1] + cv.y;
      float z2 = acc[i][2] + cv.z, z3 = acc[i][3] + cv.w;
      Z[(size_t)row * 64 + (c0 >> 1) + 0] = __floats2half2_rn(z0, z1);
      Z[(size_t)row * 64 + (c0 >> 1) + 1] = __floats2half2_rn(z2, z3);
      ls[0] += z0; ls[1] += z1; ls[2] += z2; ls[3] += z3;
      lq[0] += z0 * z0; lq[1] += z1 * z1; lq[2] += z2 * z2; lq[3] += z3 * z3;
    }
  }
  __syncthreads();  // done reading Xs, reuse as reduction scratch
  float* redS = Xs;
  float* redQ = Xs + 1024;
#pragma unroll
  for (int j = 0; j < 4; ++j) {
    redS[tr * DIMS + c0 + j] = ls[j];
    redQ[tr * DIMS + c0 + j] = lq[j];
  }
  __syncthreads();
  if (tid < DIMS) {
    float s = 0.f, q = 0.f;
#pragma unroll
    for (int t = 0; t < 8; ++t) { s += redS[t * DIMS + tid]; q += redQ[t * DIMS + tid]; }
    int sh = blockIdx.x & (NSH - 1);
    atomicAdd(&sumS[sh * DIMS + tid], s);
    atomicAdd(&sqS[sh * DIMS + tid], q);
  }
}

// ---------------- graph segment starts (node2graph is sorted) ----------------
__global__ void gstart_k(const int* __restrict__ n2g, int* __restrict__ gstart, int n, int G) {
  int i = blockIdx.x * blockDim.x + threadIdx.x;
  if (i >= n) return;
  int g = n2g[i];
  int gp = (i == 0) ? -1 : n2g[i - 1];
  for (int x = gp + 1; x <= g; ++x) gstart[x] = i;
  if (i == n - 1) {
    for (int x = g + 1; x <= G; ++x) gstart[x] = n;
  }
}

// ---------------- BN2-apply + relu + mean-pool + final 128->2 projection ----------------
__global__ __launch_bounds__(256) void pool_pred_k(
    const __half2* __restrict__ Z, const int* __restrict__ gstart,
    const float* __restrict__ a3, const float* __restrict__ b3,
    const float* __restrict__ pw, const float* __restrict__ pb,
    float* __restrict__ out) {
  int g = blockIdx.x;
  int tid = threadIdx.x;
  int l = tid & 63, w = tid >> 6;
  int f0 = 2 * l;
  float a0 = a3[f0], b0 = b3[f0], a1 = a3[f0 + 1], b1 = b3[f0 + 1];
  int s = gstart[g], e = gstart[g + 1];
  float acc0 = 0.f, acc1 = 0.f;
  for (int ni = s + w; ni < e; ni += 4) {
    float2 z = __half22float2(Z[(size_t)ni * 64 + l]);
    acc0 += fmaxf(fmaf(z.x, a0, b0), 0.f);
    acc1 += fmaxf(fmaf(z.y, a1, b1), 0.f);
  }
  float inv = 1.f / fmaxf((float)(e - s), 1.f);
  float c0 = acc0 * inv * pw[f0 * 2 + 0] + acc1 * inv * pw[(f0 + 1) * 2 + 0];
  float c1 = acc0 * inv * pw[f0 * 2 + 1] + acc1 * inv * pw[(f0 + 1) * 2 + 1];
  __shared__ float r[2][256];
  r[0][tid] = c0; r[1][tid] = c1;
  __syncthreads();
  for (int off = 128; off > 0; off >>= 1) {
    if (tid < off) { r[0][tid] += r[0][tid + off]; r[1][tid] += r[1][tid + off]; }
    __syncthreads();
  }
  if (tid == 0) {
    out[g * 2 + 0] = r[0][0] + pb[0];
    out[g * 2 + 1] = r[1][0] + pb[1];
  }
}

// ---------------- host launch ----------------
extern "C" void kernel_launch(void* const* d_in, const int* in_sizes, int n_in,
                              void* d_out, int out_size, void* d_ws, size_t ws_size,
                              hipStream_t stream) {
  const float* nfeat  = (const float*)d_in[0];
  const int*   src    = (const int*)d_in[1];
  const int*   dst    = (const int*)d_in[2];
  const int*   n2g    = (const int*)d_in[3];
  // d_in[4] = num_graphs (device scalar) — derived from out_size instead
  const float* conv_w = (const float*)d_in[5];
  const float* conv_b = (const float*)d_in[6];
  const float* gamma1 = (const float*)d_in[7];
  const float* beta1  = (const float*)d_in[8];
  const float* gamma2 = (const float*)d_in[9];
  const float* beta2  = (const float*)d_in[10];
  const float* pred_w = (const float*)d_in[11];
  const float* pred_b = (const float*)d_in[12];
  float* out = (float*)d_out;
  (void)n_in; (void)ws_size;

  const int n = in_sizes[0] / DIMS;
  const int e = in_sizes[1];
  const int g = out_size / 2;

  char* p = (char*)d_ws;
  auto alloc = [&](size_t bytes) { char* r = p; p += (bytes + 255) & ~(size_t)255; return r; };
  uint32_t* Xp  = (uint32_t*)alloc((size_t)n * 64 * 4);  // dn-scaled input rows (half2)
  uint32_t* W1  = (uint32_t*)alloc((size_t)n * 64 * 4);  // dn^2-scaled h1 rows (half2)
  uint32_t* Y2  = (uint32_t*)alloc((size_t)n * 64 * 4);  // h2 rows (half2)
  __half2*  Zh  = (__half2*)alloc((size_t)n * 64 * 4);   // matmul output rows (half2)
  float* dnorm = (float*)alloc((size_t)n * 4);
  float* wsum  = (float*)alloc((size_t)n * 4);
  float* stat  = (float*)alloc((size_t)6 * NSH * DIMS * 4);  // [S0 Q0 S1 Q1 S2 Q2] x NSH x DIMS
  float* affA  = (float*)alloc(3 * DIMS * 4);
  float* affB  = (float*)alloc(3 * DIMS * 4);
  float* Wp    = (float*)alloc(DIMS * DIMS * 4);
  float* cp    = (float*)alloc(DIMS * 4);
  int* deg_i   = (int*)alloc((size_t)n * 2 * 4);  // deg + cursor, contiguous for zeroing
  int* cursor  = deg_i + n;
  int* row_off = (int*)alloc(((size_t)n + 1) * 4);
  int* adj     = (int*)alloc((size_t)e * 4);
  int* bsum    = (int*)alloc(2048 * 4);
  int* gstart  = (int*)alloc(((size_t)g + 1) * 4);

  const int SLAB = NSH * DIMS;
  float* S0 = stat + 0 * SLAB; float* Q0 = stat + 1 * SLAB;
  float* S1 = stat + 2 * SLAB; float* Q1 = stat + 3 * SLAB;
  float* S2 = stat + 4 * SLAB; float* Q2 = stat + 5 * SLAB;

  const int nb = (n + 1023) / 1024;  // <= 256 required (n <= 262144)
  const float invn = 1.0f / (float)n;
  const int gb = (n + 3) / 4;  // one wave per node, 4 nodes per block

  zero_k<<<dim3((2 * n + 255) / 256), dim3(256), 0, stream>>>(deg_i, (size_t)2 * n, stat, (size_t)6 * SLAB);
  deg_count_k<<<dim3((e + 255) / 256), dim3(256), 0, stream>>>(dst, deg_i, e);
  dnorm_k<<<dim3((n + 255) / 256), dim3(256), 0, stream>>>(deg_i, dnorm, n);
  cvt_k<<<dim3(2048), dim3(256), 0, stream>>>(nfeat, Xp, dnorm, (size_t)n * 64);
  scan1_k<<<dim3(nb), dim3(256), 0, stream>>>(deg_i, bsum, n);
  scan2_k<<<dim3(1), dim3(256), 0, stream>>>(bsum, nb, row_off, n, e);
  scan3_k<<<dim3(nb), dim3(256), 0, stream>>>(deg_i, bsum, row_off, n);
  build_adj_k<<<dim3((e + 255) / 256), dim3(256), 0, stream>>>(src, dst, row_off, cursor, adj, e);

  // hop 1: Xp -> W1 (stats of h1 -> S0/Q0; wsum computed)
  gather_k<false><<<dim3(gb), dim3(256), 0, stream>>>(
      Xp, W1, row_off, adj, dnorm, wsum, nullptr, nullptr, S0, Q0, n);
  affine_k<<<dim3(1), dim3(DIMS), 0, stream>>>(S0, Q0, gamma1, beta1, affA + 0, affB + 0, invn);
  // hop 2: W1 -> Y2 = h2 (stats of h2 -> S1/Q1)
  gather_k<true><<<dim3(gb), dim3(256), 0, stream>>>(
      W1, Y2, row_off, adj, dnorm, wsum, affA + 0, affB + 0, S1, Q1, n);
  affine_k<<<dim3(1), dim3(DIMS), 0, stream>>>(S1, Q1, gamma1, beta1, affA + DIMS, affB + DIMS, invn);
  // fold stage-1 affine into conv weights, then Z = h2 @ Wp + cp (stats -> S2/Q2)
  foldw_k<<<dim3(DIMS), dim3(DIMS), 0, stream>>>(conv_w, conv_b, affA + DIMS, affB + DIMS, Wp, cp);
  matmul_k<<<dim3((n + 31) / 32), dim3(256), 0, stream>>>((const __half2*)Y2, Wp, cp, Zh, S2, Q2, n);
  affine_k<<<dim3(1), dim3(DIMS), 0, stream>>>(S2, Q2, gamma2, beta2, affA + 2 * DIMS, affB + 2 * DIMS, invn);
  // pooling + prediction
  gstart_k<<<dim3((n + 255) / 256), dim3(256), 0, stream>>>(n2g, gstart, n, g);
  pool_pred_k<<<dim3(g), dim3(256), 0, stream>>>(Zh, gstart, affA + 2 * DIMS, affB + 2 * DIMS,
                                                 pred_w, pred_b, out);
}